// Round 4
// baseline (137.562 us; speedup 1.0000x reference)
//
#include <hip/hip_runtime.h>
#include <math.h>

// Problem constants
#define B_ 64
#define N_ 128
#define D_ 128
#define BN_ 8192            // B_*N_
#define NG_ 50
#define CUTOFF_ 10.0f

// ---------------------------------------------------------------------------
// async global->LDS helper (16B per lane, wave-uniform LDS base + lane*16)
__device__ __forceinline__ void gl_lds16(const float* g, float* l) {
    __builtin_amdgcn_global_load_lds(
        (const __attribute__((address_space(1))) void*)(g),
        (__attribute__((address_space(3))) void*)(l), 16, 0, 0);
}

// ---------------------------------------------------------------------------
// 0. weight-fusion prep: Wf = w2 @ in_proj (128x256), bf = b2 @ in_proj (256),
//    Wd = xpw[:, :8] @ dtw (128x128)
__global__ __launch_bounds__(256) void fuse_k(const float* __restrict__ w2,
                                              const float* __restrict__ in_proj,
                                              const float* __restrict__ b2,
                                              const float* __restrict__ xpw,
                                              const float* __restrict__ dtw,
                                              float* __restrict__ Wf,
                                              float* __restrict__ bf,
                                              float* __restrict__ Wd) {
    int blk = blockIdx.x, t = threadIdx.x;
    if (blk < 128) {
        float s = 0.0f;
        #pragma unroll 8
        for (int k = 0; k < 128; k++) s = fmaf(w2[blk * 128 + k], in_proj[k * 256 + t], s);
        Wf[blk * 256 + t] = s;
    } else if (blk < 256) {
        int m = blk - 128;
        if (t < 128) {
            float s = 0.0f;
            #pragma unroll
            for (int r = 0; r < 8; r++) s = fmaf(xpw[m * 12 + r], dtw[r * 128 + t], s);
            Wd[m * 128 + t] = s;
        }
    } else {
        float s = 0.0f;
        #pragma unroll 8
        for (int k = 0; k < 128; k++) s = fmaf(b2[k], in_proj[k * 256 + t], s);
        bf[t] = s;
    }
}

// ---------------------------------------------------------------------------
// 1. RMSNorm (wave-per-row, 4 rows/block) + fused passthrough copy
// grid 2048 x 256
__global__ __launch_bounds__(256) void rms_k(const float* __restrict__ x,
                                             const float* __restrict__ w,
                                             float* __restrict__ x1,
                                             const float* __restrict__ pos,
                                             const int* __restrict__ mi,
                                             float* __restrict__ out) {
    int tid = threadIdx.x;
    int wv = tid >> 6, ln = tid & 63;
    int row = blockIdx.x * 4 + wv;
    const float2* xr = reinterpret_cast<const float2*>(x) + (size_t)row * 64;
    float2 v = xr[ln];
    float s = fmaf(v.x, v.x, v.y * v.y);
    #pragma unroll
    for (int o = 32; o > 0; o >>= 1) s += __shfl_down(s, o, 64);
    float tot = __shfl(s, 0, 64);
    float r = rsqrtf(tot * (1.0f / D_) + 1e-5f);
    float2 wv2 = reinterpret_cast<const float2*>(w)[ln];
    float2 o2 = make_float2(v.x * r * wv2.x, v.y * r * wv2.y);
    reinterpret_cast<float2*>(x1)[(size_t)row * 64 + ln] = o2;

    int g = blockIdx.x * 256 + tid;
    if (g < BN_ * 3) out[(size_t)BN_ * D_ + g] = pos[g];
    if (g < BN_) out[(size_t)BN_ * D_ + BN_ * 3 + g] = (float)mi[g];
}

// ---------------------------------------------------------------------------
// 3. adjacency: smeared adj, dense edge mask, 1/deg
__global__ __launch_bounds__(256) void adj_k(const float* __restrict__ pos,
                                             const float* __restrict__ lin_w,
                                             const float* __restrict__ lin_b,
                                             float* __restrict__ adj,
                                             float* __restrict__ emd,
                                             float* __restrict__ rdeg) {
    __shared__ float px[N_], py[N_], pz[N_];
    __shared__ float lw[NG_];
    __shared__ int degs[8];
    int b = blockIdx.y;
    int tid = threadIdx.x;
    if (tid < N_) {
        const float* p = pos + (size_t)(b * N_ + tid) * 3;
        px[tid] = p[0]; py[tid] = p[1]; pz[tid] = p[2];
    } else if (tid - N_ < NG_) {
        lw[tid - N_] = lin_w[tid - N_];
    }
    if (tid >= 248) degs[tid - 248] = 0;
    __syncthreads();
    float linb = lin_b[0];
    int j = tid & 127;
    int il = tid >> 7;
    const float DEL = 10.0f / 49.0f;
    const float COEFF = -0.5f / (DEL * DEL);
    #pragma unroll
    for (int p = 0; p < 4; p++) {
        int i = blockIdx.x * 8 + p * 2 + il;
        float dx = px[i] - px[j], dy = py[i] - py[j], dz = pz[i] - pz[j];
        float d2 = dx * dx + dy * dy + dz * dz;
        float dist = (i == j) ? 1.0f : sqrtf(d2);
        bool edge = (i != j) && (dist < CUTOFF_);
        float val = 0.0f;
        if (edge) {
            int g0 = (int)ceilf((dist - 1.75f) / DEL); if (g0 < 0) g0 = 0;
            int g1 = (int)floorf((dist + 1.75f) / DEL); if (g1 > NG_ - 1) g1 = NG_ - 1;
            float s = linb;
            for (int g = g0; g <= g1; g++) {
                float t = dist - (float)g * DEL;
                s += lw[g] * expf(COEFF * t * t);
            }
            val = s;
        }
        adj[((size_t)b * N_ + i) * N_ + j] = val;
        emd[((size_t)b * N_ + i) * N_ + j] = edge ? 1.0f : 0.0f;
        unsigned long long msk = __ballot(edge);
        if ((tid & 63) == 0) atomicAdd(&degs[p * 2 + il], __popcll(msk));
    }
    __syncthreads();
    if (tid < 8) {
        int dg = degs[tid];
        rdeg[(size_t)b * N_ + blockIdx.x * 8 + tid] = 1.0f / (float)(dg > 0 ? dg : 1);
    }
}

// ---------------------------------------------------------------------------
// Generic fp32 GEMM: C[M x ncols] = A[M x 128] @ W[128 x ncols] (+ epilogue)
// block tile 32 rows x 128 cols, thread tile 4x4, 256 threads, 80KB LDS
// (2 blocks/CU capacity; 256 blocks = 1/CU chip-wide). Register double-buffer
// on the fragment reads so LDS latency hides under FMAs.
// EPI: 0 none, 1 bias+relu, 2 bias, 3 isfinite-clean + add AUX, 4 scale AUX[row],
//      5 softplus(t + bias)
template <int EPI>
__global__ __launch_bounds__(256, 2) void gemm_k(const float* __restrict__ A,
                                                 const float* __restrict__ W,
                                                 const float* __restrict__ bias,
                                                 float* __restrict__ C,
                                                 const float* __restrict__ AUX,
                                                 int wstride, int cstride, int wbs) {
    extern __shared__ float sm[];
    float* As = sm;              // 32*128
    float* Ws = sm + 32 * 128;   // 128*128
    int tid = threadIdx.x;
    int row_base = blockIdx.x * 32;
    int col_base = blockIdx.y * 128;

    float4* As4 = reinterpret_cast<float4*>(As);
    float4* Ws4 = reinterpret_cast<float4*>(Ws);

    // stage A tile (32x128 = 1024 float4) via async DMA
    const float* Ag = A + (size_t)row_base * 128;
    #pragma unroll
    for (int i = 0; i < 4; i++) {
        int q = tid + i * 256;
        gl_lds16(Ag + q * 4, (float*)(As4 + q));
    }
    // stage W tile (128 x 128 = 4096 float4)
    const float* Wp = W + (size_t)(row_base >> 7) * wbs;
    #pragma unroll
    for (int i = 0; i < 16; i++) {
        int q = tid + i * 256;
        int r = q >> 5, cv = q & 31;
        gl_lds16(Wp + (size_t)r * wstride + col_base + cv * 4, (float*)(Ws4 + q));
    }
    __syncthreads();   // drains vmcnt for the async LDS loads

    int ct = tid & 31, rt = tid >> 5;
    int c0 = ct * 4, r0 = rt * 4;
    float acc[4][4] = {};
    float4 ac[4], wc[4], an[4], wn[4];
    #pragma unroll
    for (int i = 0; i < 4; i++) ac[i] = As4[(r0 + i) * 32 + 0];
    #pragma unroll
    for (int k = 0; k < 4; k++) wc[k] = Ws4[k * 32 + ct];

    #pragma unroll
    for (int kb = 0; kb < 32; kb++) {
        if (kb < 31) {
            #pragma unroll
            for (int i = 0; i < 4; i++) an[i] = As4[(r0 + i) * 32 + kb + 1];
            #pragma unroll
            for (int k = 0; k < 4; k++) wn[k] = Ws4[((kb + 1) * 4 + k) * 32 + ct];
        }
        #pragma unroll
        for (int kk = 0; kk < 4; kk++) {
            float a0 = (kk == 0) ? 0.f : 0.f; (void)a0;
            float af[4] = { ((const float*)&ac[0])[kk], ((const float*)&ac[1])[kk],
                            ((const float*)&ac[2])[kk], ((const float*)&ac[3])[kk] };
            const float* wf = (const float*)&wc[kk];
            #pragma unroll
            for (int i = 0; i < 4; i++)
                #pragma unroll
                for (int jj = 0; jj < 4; jj++)
                    acc[i][jj] = fmaf(af[i], wf[jj], acc[i][jj]);
        }
        if (kb < 31) {
            #pragma unroll
            for (int i = 0; i < 4; i++) ac[i] = an[i];
            #pragma unroll
            for (int k = 0; k < 4; k++) wc[k] = wn[k];
        }
    }

    #pragma unroll
    for (int i = 0; i < 4; i++) {
        int row = row_base + r0 + i;
        int col = col_base + c0;
        float v[4];
        #pragma unroll
        for (int jj = 0; jj < 4; jj++) {
            float t = acc[i][jj];
            if (EPI == 1) { t += bias[col + jj]; t = fmaxf(t, 0.0f); }
            if (EPI == 2) { t += bias[col + jj]; }
            if (EPI == 3) {
                t = isfinite(t) ? t : 0.0f;
                t += AUX[(size_t)row * 128 + col + jj];
            }
            if (EPI == 4) { t *= AUX[row]; }
            if (EPI == 5) {
                t += bias[col + jj];
                t = fmaxf(t, 0.0f) + log1pf(expf(-fabsf(t)));   // softplus
            }
            v[jj] = t;
        }
        float4 o = make_float4(v[0], v[1], v[2], v[3]);
        *reinterpret_cast<float4*>(C + (size_t)row * cstride + col) = o;
    }
}

// ---------------------------------------------------------------------------
// 8. conv1d + silu -> xc ; bc = xc @ xpw[:, 8:12]
// grid 2048 x 256 (4 rows/block via 2 iterations of 2 rows)
__global__ __launch_bounds__(256) void convsm_k(const float* __restrict__ xr,
                                                const float* __restrict__ conv_w,
                                                const float* __restrict__ conv_b,
                                                const float* __restrict__ xpw,
                                                float* __restrict__ xc,
                                                float* __restrict__ bc) {
    int tid = threadIdx.x;
    int slot = tid >> 7;         // 0..1 (row within pair)
    int d = tid & 127;
    int ln = tid & 63;
    int wv = (tid >> 6) & 1;     // wave within row
    __shared__ float red[2][2][4];
    float cw[4];
    #pragma unroll
    for (int jj = 0; jj < 4; jj++) cw[jj] = conv_w[d * 4 + jj];
    float cb = conv_b[d];
    float4 wv4 = *reinterpret_cast<const float4*>(xpw + d * 12 + 8);

    #pragma unroll
    for (int it = 0; it < 2; it++) {
        int row = blockIdx.x * 4 + it * 2 + slot;
        int bt = row & 127;
        float accv = cb;
        #pragma unroll
        for (int jj = 0; jj < 4; jj++) {
            int tt = bt + jj - 3;
            if (tt >= 0) accv = fmaf(xr[((size_t)(row + jj - 3)) * 256 + d], cw[jj], accv);
        }
        float xcv = accv / (1.0f + expf(-accv));   // silu
        xc[(size_t)row * D_ + d] = xcv;
        float p0 = xcv * wv4.x, p1 = xcv * wv4.y, p2 = xcv * wv4.z, p3 = xcv * wv4.w;
        #pragma unroll
        for (int o = 32; o > 0; o >>= 1) {
            p0 += __shfl_down(p0, o, 64);
            p1 += __shfl_down(p1, o, 64);
            p2 += __shfl_down(p2, o, 64);
            p3 += __shfl_down(p3, o, 64);
        }
        if (ln == 0) {
            red[slot][wv][0] = p0; red[slot][wv][1] = p1;
            red[slot][wv][2] = p2; red[slot][wv][3] = p3;
        }
        __syncthreads();
        if (d < 4) bc[(size_t)row * 4 + d] = red[slot][0][d] + red[slot][1][d];
        __syncthreads();
    }
}

// ---------------------------------------------------------------------------
// 10. selective scan
__global__ __launch_bounds__(256) void scan_k(const float* __restrict__ dp_,
                                              const float* __restrict__ xc,
                                              const float* __restrict__ bc,
                                              const float* __restrict__ xr,
                                              const float* __restrict__ A_log,
                                              const float* __restrict__ Dpar,
                                              float* __restrict__ yfull) {
    int g = blockIdx.x * 256 + threadIdx.x;
    int b = g >> 7, d = g & 127;
    float a1 = -expf(A_log[d * 2]);
    float a2 = -expf(A_log[d * 2 + 1]);
    float Dp = Dpar[d];
    float h1 = 0.0f, h2 = 0.0f;
    size_t base = (size_t)b * N_;
    for (int t = 0; t < N_; t++) {
        size_t row = base + t;
        float dpv = dp_[row * D_ + d];
        float xcv = xc[row * D_ + d];
        float bm0 = bc[row * 4 + 0], bm1 = bc[row * 4 + 1];
        float cm0 = bc[row * 4 + 2], cm1 = bc[row * 4 + 3];
        float e1 = expf(dpv * a1), e2 = expf(dpv * a2);
        float bu = dpv * xcv;
        h1 = fmaf(e1, h1, bu * bm0);
        h2 = fmaf(e2, h2, bu * bm1);
        float y = fmaf(h1, cm0, h2 * cm1);
        float r = xr[row * 256 + 128 + d];
        float yv = fmaf(xcv, Dp, y) * (r / (1.0f + expf(-r)));
        yfull[row * D_ + d] = yv;
    }
}

// ---------------------------------------------------------------------------
extern "C" void kernel_launch(void* const* d_in, const int* in_sizes, int n_in,
                              void* d_out, int out_size, void* d_ws, size_t ws_size,
                              hipStream_t stream) {
    const float* x        = (const float*)d_in[0];
    const float* pos      = (const float*)d_in[1];
    const int*   mi       = (const int*)d_in[2];
    const float* norm_w   = (const float*)d_in[4];
    const float* w1       = (const float*)d_in[5];
    const float* b1       = (const float*)d_in[6];
    const float* w2       = (const float*)d_in[7];
    const float* b2       = (const float*)d_in[8];
    const float* lin_w    = (const float*)d_in[9];
    const float* lin_b    = (const float*)d_in[10];
    const float* in_proj  = (const float*)d_in[11];
    const float* conv_w   = (const float*)d_in[12];
    const float* conv_b   = (const float*)d_in[13];
    const float* xpw      = (const float*)d_in[14];
    const float* dtw      = (const float*)d_in[15];
    const float* dtb      = (const float*)d_in[16];
    const float* A_log    = (const float*)d_in[17];
    const float* Dpar     = (const float*)d_in[18];
    const float* out_proj = (const float*)d_in[19];

    float* out = (float*)d_out;
    float* ws  = (float*)d_ws;
    const size_t M1 = 1048576;           // 1M floats
    float* x1  = ws;                     // x1 (live to end)
    float* adj = ws + M1;                // adj
    float* hx  = ws + 2 * M1;            // h -> delta -> yfull
    float* ax  = ws + 3 * M1;            // agg -> xc
    float* xr  = ws + 4 * M1;            // in_proj output (xm|res), 2M
    float* dp  = ws + 6 * M1;            // em_dense -> delta_p
    float* bc  = ws + 7 * M1;            // 32K floats
    float* rdeg = ws + 7 * M1 + 32768;   // 8192
    float* Wf  = ws + 7 * M1 + 65536;    // 128*256
    float* bf  = Wf + 32768;             // 256
    float* Wd  = bf + 256;               // 128*128

    const size_t gsm = (32 * 128 + 128 * 128) * sizeof(float);   // 80 KB

    fuse_k<<<257, 256, 0, stream>>>(w2, in_proj, b2, xpw, dtw, Wf, bf, Wd);
    rms_k<<<2048, 256, 0, stream>>>(x, norm_w, x1, pos, mi, out);
    adj_k<<<dim3(16, B_), 256, 0, stream>>>(pos, lin_w, lin_b, adj, dp, rdeg);
    // h = relu(x1 @ w1 + b1)
    gemm_k<1><<<dim3(256, 1), 256, gsm, stream>>>(x1, w1, b1, hx, nullptr, 128, 128, 0);
    // agg = (em_dense @ h[b]) * rdeg
    gemm_k<4><<<dim3(256, 1), 256, gsm, stream>>>(dp, hx, nullptr, ax, rdeg, 128, 128, N_ * N_);
    // xr = agg @ Wf + bf   (fused w2+in_proj)
    gemm_k<2><<<dim3(256, 2), 256, gsm, stream>>>(ax, Wf, bf, xr, nullptr, 256, 256, 0);
    // conv + silu -> xc(ax);  bc side output
    convsm_k<<<2048, 256, 0, stream>>>(xr, conv_w, conv_b, xpw, ax, bc);
    // delta = softplus(xc @ Wd + dtb)
    gemm_k<5><<<dim3(256, 1), 256, gsm, stream>>>(ax, Wd, dtb, hx, nullptr, 128, 128, 0);
    // delta_p = delta @ adj[b]
    gemm_k<0><<<dim3(256, 1), 256, gsm, stream>>>(hx, adj, nullptr, dp, nullptr, 128, 128, N_ * N_);
    // scan -> yfull
    scan_k<<<BN_ / 256, 256, 0, stream>>>(dp, ax, bc, xr, A_log, Dpar, hx);
    // out = clean(yfull @ out_proj) + x1
    gemm_k<3><<<dim3(256, 1), 256, gsm, stream>>>(hx, out_proj, nullptr, out, x1, 128, 128, 0);
}

// Round 5
// 113.615 us; speedup vs baseline: 1.2108x; 1.2108x over previous
//
#include <hip/hip_runtime.h>
#include <math.h>

// Problem constants
#define B_ 64
#define N_ 128
#define D_ 128
#define BN_ 8192            // B_*N_
#define NG_ 50
#define CUTOFF_ 10.0f

typedef __attribute__((ext_vector_type(8))) short short8v;   // 8 bf16 (4 VGPR)
typedef __attribute__((ext_vector_type(4))) float f32x4;
#define MFMA16 __builtin_amdgcn_mfma_f32_16x16x32_bf16

// bf16 helpers (bit-level, RTNE)
__device__ __forceinline__ float bf2f(unsigned short h) {
    return __builtin_bit_cast(float, ((unsigned int)h) << 16);
}
__device__ __forceinline__ unsigned short f2bf(float f) {
    unsigned int u = __builtin_bit_cast(unsigned int, f);
    return (unsigned short)((u + 0x7FFFu + ((u >> 16) & 1u)) >> 16);
}
__device__ __forceinline__ void splitbf(float x, unsigned short& h, unsigned short& l) {
    h = f2bf(x);
    l = f2bf(x - bf2f(h));
}

// async global->LDS, 16B per lane (lds dest = wave base + lane*16)
__device__ __forceinline__ void gl_lds(const void* g, void* l) {
    __builtin_amdgcn_global_load_lds(
        (const __attribute__((address_space(1))) void*)g,
        (__attribute__((address_space(3))) void*)l, 16, 0, 0);
}

// ---------------------------------------------------------------------------
// 0. weight prep: transposed bf16 hi/lo planes for all static B-matrices.
// w1T/WdT/opT: [128][128]; WfT: [256][128]; bf fp32[256].
__global__ __launch_bounds__(256) void prep_k(const float* __restrict__ w1,
                                              const float* __restrict__ w2,
                                              const float* __restrict__ b2,
                                              const float* __restrict__ in_proj,
                                              const float* __restrict__ xpw,
                                              const float* __restrict__ dtw,
                                              const float* __restrict__ out_proj,
                                              unsigned short* __restrict__ w1Th,
                                              unsigned short* __restrict__ w1Tl,
                                              unsigned short* __restrict__ WdTh,
                                              unsigned short* __restrict__ WdTl,
                                              unsigned short* __restrict__ opTh,
                                              unsigned short* __restrict__ opTl,
                                              unsigned short* __restrict__ WfTh,
                                              unsigned short* __restrict__ WfTl,
                                              float* __restrict__ bfv) {
    int blk = blockIdx.x, t = threadIdx.x;
    if (blk < 128) {                       // w1T[n=t][k=blk]
        if (t < 128) {
            unsigned short h, l;
            splitbf(w1[blk * 128 + t], h, l);
            w1Th[t * 128 + blk] = h; w1Tl[t * 128 + blk] = l;
        }
    } else if (blk < 256) {                // WdT[n=t][m]
        int m = blk - 128;
        if (t < 128) {
            float s = 0.0f;
            #pragma unroll
            for (int r = 0; r < 8; r++) s = fmaf(xpw[m * 12 + r], dtw[r * 128 + t], s);
            unsigned short h, l; splitbf(s, h, l);
            WdTh[t * 128 + m] = h; WdTl[t * 128 + m] = l;
        }
    } else if (blk < 384) {                // opT[n=t][k]
        int k = blk - 256;
        if (t < 128) {
            unsigned short h, l;
            splitbf(out_proj[k * 128 + t], h, l);
            opTh[t * 128 + k] = h; opTl[t * 128 + k] = l;
        }
    } else if (blk < 512) {                // WfT[n=t][k],  t in [0,256)
        int k = blk - 384;
        float s = 0.0f;
        #pragma unroll 8
        for (int j = 0; j < 128; j++) s = fmaf(w2[k * 128 + j], in_proj[j * 256 + t], s);
        unsigned short h, l; splitbf(s, h, l);
        WfTh[t * 128 + k] = h; WfTl[t * 128 + k] = l;
    } else {                               // bf
        float s = 0.0f;
        #pragma unroll 8
        for (int j = 0; j < 128; j++) s = fmaf(b2[j], in_proj[j * 256 + t], s);
        bfv[t] = s;
    }
}

// ---------------------------------------------------------------------------
// 1. RMSNorm (wave-per-row) + hi/lo planes + fused passthrough copy
__global__ __launch_bounds__(256) void rms_k(const float* __restrict__ x,
                                             const float* __restrict__ w,
                                             float* __restrict__ x1,
                                             unsigned short* __restrict__ x1h,
                                             unsigned short* __restrict__ x1l,
                                             const float* __restrict__ pos,
                                             const int* __restrict__ mi,
                                             float* __restrict__ out) {
    int tid = threadIdx.x;
    int wv = tid >> 6, ln = tid & 63;
    int row = blockIdx.x * 4 + wv;
    const float2* xr = reinterpret_cast<const float2*>(x) + (size_t)row * 64;
    float2 v = xr[ln];
    float s = fmaf(v.x, v.x, v.y * v.y);
    #pragma unroll
    for (int o = 32; o > 0; o >>= 1) s += __shfl_down(s, o, 64);
    float tot = __shfl(s, 0, 64);
    float r = rsqrtf(tot * (1.0f / D_) + 1e-5f);
    float2 wv2 = reinterpret_cast<const float2*>(w)[ln];
    float o0 = v.x * r * wv2.x, o1 = v.y * r * wv2.y;
    reinterpret_cast<float2*>(x1)[(size_t)row * 64 + ln] = make_float2(o0, o1);
    unsigned short h0, l0, h1, l1;
    splitbf(o0, h0, l0); splitbf(o1, h1, l1);
    reinterpret_cast<ushort2*>(x1h)[(size_t)row * 64 + ln] = make_ushort2(h0, h1);
    reinterpret_cast<ushort2*>(x1l)[(size_t)row * 64 + ln] = make_ushort2(l0, l1);

    int g = blockIdx.x * 256 + tid;
    if (g < BN_ * 3) out[(size_t)BN_ * D_ + g] = pos[g];
    if (g < BN_) out[(size_t)BN_ * D_ + BN_ * 3 + g] = (float)mi[g];
}

// ---------------------------------------------------------------------------
// 3. adjacency: smeared adj hi/lo (symmetric => also its own transpose),
//    em hi plane (exact 1.0), 1/deg
__global__ __launch_bounds__(256) void adj_k(const float* __restrict__ pos,
                                             const float* __restrict__ lin_w,
                                             const float* __restrict__ lin_b,
                                             unsigned short* __restrict__ adjh,
                                             unsigned short* __restrict__ adjl,
                                             unsigned short* __restrict__ emh,
                                             float* __restrict__ rdeg) {
    __shared__ float px[N_], py[N_], pz[N_];
    __shared__ float lw[NG_];
    __shared__ int degs[8];
    int b = blockIdx.y;
    int tid = threadIdx.x;
    if (tid < N_) {
        const float* p = pos + (size_t)(b * N_ + tid) * 3;
        px[tid] = p[0]; py[tid] = p[1]; pz[tid] = p[2];
    } else if (tid - N_ < NG_) {
        lw[tid - N_] = lin_w[tid - N_];
    }
    if (tid >= 248) degs[tid - 248] = 0;
    __syncthreads();
    float linb = lin_b[0];
    int j = tid & 127;
    int il = tid >> 7;
    const float DEL = 10.0f / 49.0f;
    const float COEFF = -0.5f / (DEL * DEL);
    #pragma unroll
    for (int p = 0; p < 4; p++) {
        int i = blockIdx.x * 8 + p * 2 + il;
        float dx = px[i] - px[j], dy = py[i] - py[j], dz = pz[i] - pz[j];
        float d2 = dx * dx + dy * dy + dz * dz;
        float dist = (i == j) ? 1.0f : sqrtf(d2);
        bool edge = (i != j) && (dist < CUTOFF_);
        float val = 0.0f;
        if (edge) {
            int g0 = (int)ceilf((dist - 1.75f) / DEL); if (g0 < 0) g0 = 0;
            int g1 = (int)floorf((dist + 1.75f) / DEL); if (g1 > NG_ - 1) g1 = NG_ - 1;
            float s = linb;
            for (int g = g0; g <= g1; g++) {
                float t = dist - (float)g * DEL;
                s += lw[g] * expf(COEFF * t * t);
            }
            val = s;
        }
        size_t idx = ((size_t)b * N_ + i) * N_ + j;
        unsigned short h, l; splitbf(val, h, l);
        adjh[idx] = h; adjl[idx] = l;
        emh[idx] = edge ? 0x3F80 : 0;      // bf16 1.0 / 0.0
        unsigned long long msk = __ballot(edge);
        if ((tid & 63) == 0) atomicAdd(&degs[p * 2 + il], __popcll(msk));
    }
    __syncthreads();
    if (tid < 8) {
        int dg = degs[tid];
        rdeg[(size_t)b * N_ + blockIdx.x * 8 + tid] = 1.0f / (float)(dg > 0 ? dg : 1);
    }
}

// ---------------------------------------------------------------------------
// Split-bf16 MFMA GEMM: C[M x N] = A[M x 128] @ B[128 x N]  (fp32-equiv via
// Ah*Bh + Ah*Bl + Al*Bh). A planes row-major [M][128]; B given TRANSPOSED
// [N][128] (k-contiguous), optional per-batch stride wbs.
// Block tile 32 rows x 64 cols, 4 waves (wave = 16 cols), 48KB LDS, XOR-swizzled.
// EPI: 0 fp32 store | 1 relu+bias -> hT planes (batched [b][n][k]) |
//      2 *AUX[row] -> planes | 3 +bias -> fp32 | 4 softplus(+bias) -> planes |
//      5 isfinite-clean + AUX residual -> fp32
#define AHOFF 0
#define ALOFF 8192
#define BHOFF 16384
#define BLOFF 32768
template <int EPI, bool ALO>
__global__ __launch_bounds__(256, 3) void mgemm_k(
        const unsigned short* __restrict__ Ah, const unsigned short* __restrict__ Al,
        const unsigned short* __restrict__ BTh, const unsigned short* __restrict__ BTl,
        const float* __restrict__ bias, const float* __restrict__ AUX,
        float* __restrict__ Cf, unsigned short* __restrict__ Ch,
        unsigned short* __restrict__ Cl, int cstride, int wbs) {
    extern __shared__ char sm[];
    int tid = threadIdx.x;
    int row_base = blockIdx.x * 32;
    int col_base = blockIdx.y * 64;

    const unsigned short* pBh = BTh;
    const unsigned short* pBl = BTl;
    if (wbs) {
        size_t bo = (size_t)(row_base >> 7) * (size_t)wbs;
        pBh += bo; pBl += bo;
    }

    // stage A planes (32x128 bf16 = 8KB each): swizzled source, linear LDS dest
    #pragma unroll
    for (int i = 0; i < 2; i++) {
        int s = tid + i * 256;
        int row = s >> 4, inner = s & 15;
        int gb = (inner * 16) ^ ((row & 7) << 4);
        size_t gsrc = (size_t)(row_base + row) * 256 + gb;   // bytes
        gl_lds((const char*)Ah + gsrc, sm + AHOFF + s * 16);
        if (ALO) gl_lds((const char*)Al + gsrc, sm + ALOFF + s * 16);
    }
    // stage BT planes (64x128 bf16 = 16KB each)
    #pragma unroll
    for (int i = 0; i < 4; i++) {
        int s = tid + i * 256;
        int n = s >> 4, inner = s & 15;
        int gb = (inner * 16) ^ ((n & 7) << 4);
        size_t gsrc = (size_t)(col_base + n) * 256 + gb;     // bytes
        gl_lds((const char*)pBh + gsrc, sm + BHOFF + s * 16);
        gl_lds((const char*)pBl + gsrc, sm + BLOFF + s * 16);
    }
    __syncthreads();

    int w = tid >> 6, l = tid & 63;
    int rlow = l & 15, kb_lane = (l >> 4) * 16;   // byte offset within 64B k-frag
    int nB = w * 16 + rlow;
    int nswz = (nB & 7) << 4;
    f32x4 acc[2] = {{0.f, 0.f, 0.f, 0.f}, {0.f, 0.f, 0.f, 0.f}};
    #pragma unroll
    for (int kb = 0; kb < 4; kb++) {
        int kbyte = kb * 64 + kb_lane;
        short8v bh = *(const short8v*)(sm + BHOFF + nB * 256 + (kbyte ^ nswz));
        short8v bl = *(const short8v*)(sm + BLOFF + nB * 256 + (kbyte ^ nswz));
        #pragma unroll
        for (int rf = 0; rf < 2; rf++) {
            int ra = rf * 16 + rlow;
            int aswz = (ra & 7) << 4;
            short8v ah = *(const short8v*)(sm + AHOFF + ra * 256 + (kbyte ^ aswz));
            acc[rf] = MFMA16(ah, bh, acc[rf], 0, 0, 0);
            acc[rf] = MFMA16(ah, bl, acc[rf], 0, 0, 0);
            if (ALO) {
                short8v al_ = *(const short8v*)(sm + ALOFF + ra * 256 + (kbyte ^ aswz));
                acc[rf] = MFMA16(al_, bh, acc[rf], 0, 0, 0);
            }
        }
    }

    // epilogue: C/D layout col = lane&15, row = (lane>>4)*4 + q   [m89]
    int colg = col_base + w * 16 + rlow;
    #pragma unroll
    for (int rf = 0; rf < 2; rf++) {
        int row0 = row_base + rf * 16 + (l >> 4) * 4;
        if (EPI == 1) {
            float b_ = bias[colg];
            unsigned short hh[4], ll[4];
            #pragma unroll
            for (int q = 0; q < 4; q++) {
                float t = fmaxf(acc[rf][q] + b_, 0.0f);
                splitbf(t, hh[q], ll[q]);
            }
            size_t bb = (size_t)(row0 >> 7) * 16384 + (size_t)colg * 128 + (row0 & 127);
            *reinterpret_cast<ushort4*>(Ch + bb) = make_ushort4(hh[0], hh[1], hh[2], hh[3]);
            *reinterpret_cast<ushort4*>(Cl + bb) = make_ushort4(ll[0], ll[1], ll[2], ll[3]);
        } else {
            #pragma unroll
            for (int q = 0; q < 4; q++) {
                int row = row0 + q;
                float t = acc[rf][q];
                if (EPI == 2) {
                    t *= AUX[row];
                    unsigned short h, lo; splitbf(t, h, lo);
                    Ch[(size_t)row * 128 + colg] = h;
                    Cl[(size_t)row * 128 + colg] = lo;
                }
                if (EPI == 3) {
                    t += bias[colg];
                    Cf[(size_t)row * cstride + colg] = t;
                }
                if (EPI == 4) {
                    t += bias[colg];
                    t = fmaxf(t, 0.0f) + log1pf(expf(-fabsf(t)));
                    unsigned short h, lo; splitbf(t, h, lo);
                    Ch[(size_t)row * 128 + colg] = h;
                    Cl[(size_t)row * 128 + colg] = lo;
                }
                if (EPI == 0) {
                    Cf[(size_t)row * cstride + colg] = t;
                }
                if (EPI == 5) {
                    t = isfinite(t) ? t : 0.0f;
                    t += AUX[(size_t)row * 128 + colg];
                    Cf[(size_t)row * cstride + colg] = t;
                }
            }
        }
    }
}

// ---------------------------------------------------------------------------
// 8. conv1d + silu -> xc fp32 + hi/lo planes ; bc = xc @ xpw[:, 8:12]
__global__ __launch_bounds__(256) void convsm_k(const float* __restrict__ xr,
                                                const float* __restrict__ conv_w,
                                                const float* __restrict__ conv_b,
                                                const float* __restrict__ xpw,
                                                float* __restrict__ xc,
                                                unsigned short* __restrict__ xch,
                                                unsigned short* __restrict__ xcl,
                                                float* __restrict__ bc) {
    int tid = threadIdx.x;
    int slot = tid >> 7;
    int d = tid & 127;
    int ln = tid & 63;
    int wv = (tid >> 6) & 1;
    __shared__ float red[2][2][4];
    float cw[4];
    #pragma unroll
    for (int jj = 0; jj < 4; jj++) cw[jj] = conv_w[d * 4 + jj];
    float cb = conv_b[d];
    float4 wv4 = *reinterpret_cast<const float4*>(xpw + d * 12 + 8);

    #pragma unroll
    for (int it = 0; it < 2; it++) {
        int row = blockIdx.x * 4 + it * 2 + slot;
        int bt = row & 127;
        float accv = cb;
        #pragma unroll
        for (int jj = 0; jj < 4; jj++) {
            int tt = bt + jj - 3;
            if (tt >= 0) accv = fmaf(xr[((size_t)(row + jj - 3)) * 256 + d], cw[jj], accv);
        }
        float xcv = accv / (1.0f + expf(-accv));   // silu
        xc[(size_t)row * D_ + d] = xcv;
        unsigned short h, lo; splitbf(xcv, h, lo);
        xch[(size_t)row * D_ + d] = h;
        xcl[(size_t)row * D_ + d] = lo;
        float p0 = xcv * wv4.x, p1 = xcv * wv4.y, p2 = xcv * wv4.z, p3 = xcv * wv4.w;
        #pragma unroll
        for (int o = 32; o > 0; o >>= 1) {
            p0 += __shfl_down(p0, o, 64);
            p1 += __shfl_down(p1, o, 64);
            p2 += __shfl_down(p2, o, 64);
            p3 += __shfl_down(p3, o, 64);
        }
        if (ln == 0) {
            red[slot][wv][0] = p0; red[slot][wv][1] = p1;
            red[slot][wv][2] = p2; red[slot][wv][3] = p3;
        }
        __syncthreads();
        if (d < 4) bc[(size_t)row * 4 + d] = red[slot][0][d] + red[slot][1][d];
        __syncthreads();
    }
}

// ---------------------------------------------------------------------------
// 10. selective scan -> yfull hi/lo planes
__global__ __launch_bounds__(256) void scan_k(const float* __restrict__ dp_,
                                              const float* __restrict__ xc,
                                              const float* __restrict__ bc,
                                              const float* __restrict__ xr,
                                              const float* __restrict__ A_log,
                                              const float* __restrict__ Dpar,
                                              unsigned short* __restrict__ yh,
                                              unsigned short* __restrict__ yl) {
    int g = blockIdx.x * 256 + threadIdx.x;
    int b = g >> 7, d = g & 127;
    float a1 = -expf(A_log[d * 2]);
    float a2 = -expf(A_log[d * 2 + 1]);
    float Dp = Dpar[d];
    float h1 = 0.0f, h2 = 0.0f;
    size_t base = (size_t)b * N_;
    for (int t = 0; t < N_; t++) {
        size_t row = base + t;
        float dpv = dp_[row * D_ + d];
        float xcv = xc[row * D_ + d];
        float bm0 = bc[row * 4 + 0], bm1 = bc[row * 4 + 1];
        float cm0 = bc[row * 4 + 2], cm1 = bc[row * 4 + 3];
        float e1 = expf(dpv * a1), e2 = expf(dpv * a2);
        float bu = dpv * xcv;
        h1 = fmaf(e1, h1, bu * bm0);
        h2 = fmaf(e2, h2, bu * bm1);
        float y = fmaf(h1, cm0, h2 * cm1);
        float r = xr[row * 256 + 128 + d];
        float yv = fmaf(xcv, Dp, y) * (r / (1.0f + expf(-r)));
        unsigned short hh, ll; splitbf(yv, hh, ll);
        yh[row * D_ + d] = hh;
        yl[row * D_ + d] = ll;
    }
}

// ---------------------------------------------------------------------------
extern "C" void kernel_launch(void* const* d_in, const int* in_sizes, int n_in,
                              void* d_out, int out_size, void* d_ws, size_t ws_size,
                              hipStream_t stream) {
    const float* x        = (const float*)d_in[0];
    const float* pos      = (const float*)d_in[1];
    const int*   mi       = (const int*)d_in[2];
    const float* norm_w   = (const float*)d_in[4];
    const float* w1       = (const float*)d_in[5];
    const float* b1       = (const float*)d_in[6];
    const float* w2       = (const float*)d_in[7];
    const float* b2       = (const float*)d_in[8];
    const float* lin_w    = (const float*)d_in[9];
    const float* lin_b    = (const float*)d_in[10];
    const float* in_proj  = (const float*)d_in[11];
    const float* conv_w   = (const float*)d_in[12];
    const float* conv_b   = (const float*)d_in[13];
    const float* xpw      = (const float*)d_in[14];
    const float* dtw      = (const float*)d_in[15];
    const float* dtb      = (const float*)d_in[16];
    const float* A_log    = (const float*)d_in[17];
    const float* Dpar     = (const float*)d_in[18];
    const float* out_proj = (const float*)d_in[19];

    float* out = (float*)d_out;
    char* base = (char*)d_ws;
    const size_t MB = 1u << 20;
    const size_t PL = 1048576;            // elements per plane

    float* x1   = (float*)(base);                      // 4MB fp32
    float* xr   = (float*)(base + 4 * MB);             // 8MB fp32
    float* dp   = (float*)(base + 12 * MB);            // 4MB fp32
    float* xc   = (float*)(base + 16 * MB);            // 4MB fp32
    float* bc   = (float*)(base + 20 * MB);            // 128KB
    float* rdeg = (float*)(base + 20 * MB + 131072);   // 32KB

    unsigned short* P = (unsigned short*)(base + 21 * MB);
    unsigned short* x1h  = P +  0 * PL;
    unsigned short* x1l  = P +  1 * PL;
    unsigned short* hTh  = P +  2 * PL;   // [b][n][k]
    unsigned short* hTl  = P +  3 * PL;
    unsigned short* aggh = P +  4 * PL;
    unsigned short* aggl = P +  5 * PL;
    unsigned short* xch  = P +  6 * PL;
    unsigned short* xcl  = P +  7 * PL;
    unsigned short* dlh  = P +  8 * PL;
    unsigned short* dll  = P +  9 * PL;
    unsigned short* yh   = P + 10 * PL;
    unsigned short* yl   = P + 11 * PL;
    unsigned short* adjh = P + 12 * PL;   // symmetric => also B^T
    unsigned short* adjl = P + 13 * PL;
    unsigned short* emh  = P + 14 * PL;

    unsigned short* W = (unsigned short*)(base + 52 * MB);
    unsigned short* w1Th = W;
    unsigned short* w1Tl = W + 16384;
    unsigned short* WdTh = W + 2 * 16384;
    unsigned short* WdTl = W + 3 * 16384;
    unsigned short* opTh = W + 4 * 16384;
    unsigned short* opTl = W + 5 * 16384;
    unsigned short* WfTh = W + 6 * 16384;          // [256][128]
    unsigned short* WfTl = W + 6 * 16384 + 32768;
    float* bfv = (float*)(W + 6 * 16384 + 2 * 32768);

    const size_t gsm = 49152;   // 48KB: Ah 8K | Al 8K | BTh 16K | BTl 16K

    prep_k<<<513, 256, 0, stream>>>(w1, w2, b2, in_proj, xpw, dtw, out_proj,
                                    w1Th, w1Tl, WdTh, WdTl, opTh, opTl, WfTh, WfTl, bfv);
    rms_k<<<2048, 256, 0, stream>>>(x, norm_w, x1, x1h, x1l, pos, mi, out);
    adj_k<<<dim3(16, B_), 256, 0, stream>>>(pos, lin_w, lin_b, adjh, adjl, emh, rdeg);
    // h = relu(x1 @ w1 + b1) -> hT planes
    mgemm_k<1, true><<<dim3(256, 2), 256, gsm, stream>>>(
        x1h, x1l, w1Th, w1Tl, b1, nullptr, nullptr, hTh, hTl, 128, 0);
    // agg = (em @ h[b]) * rdeg -> planes   (em exact: 2-term)
    mgemm_k<2, false><<<dim3(256, 2), 256, gsm, stream>>>(
        emh, emh, hTh, hTl, nullptr, rdeg, nullptr, aggh, aggl, 128, N_ * N_);
    // xr = agg @ Wf + bf -> fp32 (N=256)
    mgemm_k<3, true><<<dim3(256, 4), 256, gsm, stream>>>(
        aggh, aggl, WfTh, WfTl, bfv, nullptr, xr, nullptr, nullptr, 256, 0);
    // conv + silu -> xc (+planes), bc
    convsm_k<<<2048, 256, 0, stream>>>(xr, conv_w, conv_b, xpw, xc, xch, xcl, bc);
    // delta = softplus(xc @ Wd + dtb) -> planes
    mgemm_k<4, true><<<dim3(256, 2), 256, gsm, stream>>>(
        xch, xcl, WdTh, WdTl, dtb, nullptr, nullptr, dlh, dll, 128, 0);
    // dp = delta @ adj[b] -> fp32   (adj symmetric => adj planes are B^T)
    mgemm_k<0, true><<<dim3(256, 2), 256, gsm, stream>>>(
        dlh, dll, adjh, adjl, nullptr, nullptr, dp, nullptr, nullptr, 128, N_ * N_);
    // scan -> y planes
    scan_k<<<BN_ / 256, 256, 0, stream>>>(dp, xc, bc, xr, A_log, Dpar, yh, yl);
    // out = clean(y @ out_proj) + x1 -> d_out
    mgemm_k<5, true><<<dim3(256, 2), 256, gsm, stream>>>(
        yh, yl, opTh, opTl, nullptr, x1, out, nullptr, nullptr, 128, 0);
}